// Round 1
// baseline (395.380 us; speedup 1.0000x reference)
//
#include <hip/hip_runtime.h>
#include <hip/hip_bf16.h>
#include <stdint.h>

#define DD 2048
#define SS 16384
#define HH 250

typedef __attribute__((ext_vector_type(8))) short bf16x8;
typedef __attribute__((ext_vector_type(4))) short bf16x4;
typedef __attribute__((ext_vector_type(4))) float f32x4;

__device__ __forceinline__ unsigned short f2bf(float f){
  union { float f; uint32_t u; } v; v.f = f;
  uint32_t u = v.u;
  return (unsigned short)((u + 0x7fffu + ((u >> 16) & 1u)) >> 16);
}
__device__ __forceinline__ float fast_tanh(float x){
  return 1.0f - 2.0f / (1.0f + __expf(2.0f * x));
}
__device__ __forceinline__ void gl_lds16(const void* g, void* l){
  __builtin_amdgcn_global_load_lds((const __attribute__((address_space(1))) void*)g,
                                   (__attribute__((address_space(3))) void*)l, 16, 0, 0);
}

// ---------- converts ----------
__global__ void conv_wctx_kernel(const float* __restrict__ w, unsigned short* __restrict__ o){
  const int n8 = (DD * DD) / 8;
  for(int i = blockIdx.x * 256 + threadIdx.x; i < n8; i += gridDim.x * 256){
    const float4* p = (const float4*)(w + (size_t)i * 8);
    float4 a = p[0], b = p[1];
    bf16x8 v;
    v[0]=(short)f2bf(a.x); v[1]=(short)f2bf(a.y); v[2]=(short)f2bf(a.z); v[3]=(short)f2bf(a.w);
    v[4]=(short)f2bf(b.x); v[5]=(short)f2bf(b.y); v[6]=(short)f2bf(b.z); v[7]=(short)f2bf(b.w);
    *(bf16x8*)(o + (size_t)i * 8) = v;
  }
}

__global__ void conv_wp1a_kernel(const float* __restrict__ w, unsigned short* __restrict__ o){
  int g = blockIdx.x * 256 + threadIdx.x;      // 65536 threads, 8 elems each -> [256][2048]
  int row = g >> 8, col = (g & 255) * 8;
  const float* s = w + (size_t)row * (3 * DD) + col;
  bf16x8 v;
  #pragma unroll
  for(int j = 0; j < 8; j++) v[j] = (row < HH) ? (short)f2bf(s[j]) : (short)0;
  *(bf16x8*)(o + (size_t)g * 8) = v;
}

// ---------- small precompute ----------
__global__ void vec_kernel(const float* __restrict__ s_prev, const float* __restrict__ cmr,
                           const float* __restrict__ Wq, const float* __restrict__ bq,
                           const float* __restrict__ Winfo,
                           float* __restrict__ twq, float* __restrict__ tdh)
{
  int wid = threadIdx.x >> 6, lane = threadIdx.x & 63;
  bool isq = blockIdx.x < 512;
  int r = (isq ? blockIdx.x : blockIdx.x - 512) * 4 + wid;
  const float* M = (isq ? Wq : Winfo) + (size_t)r * DD;
  const float* x = isq ? s_prev : cmr;
  float s = 0.f;
  for(int i = lane; i < DD; i += 64) s += M[i] * x[i];
  #pragma unroll
  for(int o = 32; o; o >>= 1) s += __shfl_xor(s, o);
  if(lane == 0){
    if(isq) twq[r] = fast_tanh(s + bq[r]);
    else    tdh[r] = fast_tanh(s);
  }
}

__global__ void bias2_kernel(const float* __restrict__ wp1, const float* __restrict__ bp1,
                             const float* __restrict__ twq, const float* __restrict__ tdh,
                             float* __restrict__ bias2)
{
  int h = blockIdx.x * 4 + (threadIdx.x >> 6);  // 64 blocks -> h in [0,256)
  int lane = threadIdx.x & 63;
  if(h >= HH){ if(lane == 0) bias2[h] = 0.f; return; }
  const float* r1 = wp1 + (size_t)h * (3 * DD) + DD;
  const float* r2 = wp1 + (size_t)h * (3 * DD) + 2 * DD;
  float s = 0.f;
  for(int i = lane; i < DD; i += 64) s += r1[i] * twq[i] + r2[i] * tdh[i];
  #pragma unroll
  for(int o = 32; o; o >>= 1) s += __shfl_xor(s, o);
  if(lane == 0) bias2[h] = s + bp1[h];
}

// ---------- gemmA: tanh(enc @ W_ctx^T) -> bf16 [S][D] ----------
__global__ __launch_bounds__(256) void gemmA_kernel(
    const float* __restrict__ A, const unsigned short* __restrict__ B,
    unsigned short* __restrict__ Ct)
{
  __shared__ unsigned short At[128 * 64];   // 16 KB
  __shared__ unsigned short Bt[128 * 64];   // 16 KB
  const int tid = threadIdx.x;
  const int lane = tid & 63, w = tid >> 6;
  const int n0 = blockIdx.x * 128, m0 = blockIdx.y * 128;  // n-inner for W_ctx L2 reuse
  const int wm = (w >> 1) * 64, wn = (w & 1) * 64;

  f32x4 acc[4][4] = {};

  for(int kt = 0; kt < DD; kt += 64){
    __syncthreads();
    // B tile via async global->LDS (bf16 already)
    #pragma unroll
    for(int i = 0; i < 4; i++){
      int off = (w * 4 + i) * 1024 + lane * 16;
      int row = off >> 7, cb = off & 127;
      gl_lds16(B + (size_t)(n0 + row) * DD + kt + (cb >> 1),
               (char*)Bt + (w * 4 + i) * 1024);
    }
    // A tile: f32 -> bf16 reg staging, coalesced 16B chunks
    #pragma unroll
    for(int j = 0; j < 8; j++){
      int c = tid + 256 * j;                 // [0,2048): 16B-chunk id of the f32 tile
      int row = c >> 4, c4 = (c & 15) * 4;
      float4 v = *(const float4*)(A + (size_t)(m0 + row) * DD + kt + c4);
      bf16x4 p;
      p[0]=(short)f2bf(v.x); p[1]=(short)f2bf(v.y); p[2]=(short)f2bf(v.z); p[3]=(short)f2bf(v.w);
      *(bf16x4*)(At + row * 64 + c4) = p;
    }
    __syncthreads();
    #pragma unroll
    for(int ks = 0; ks < 2; ks++){
      const int kb = ks * 32 + (lane >> 4) * 8;
      bf16x8 af[4], bv[4];
      #pragma unroll
      for(int i = 0; i < 4; i++){
        af[i] = *(const bf16x8*)(At + (wm + i * 16 + (lane & 15)) * 64 + kb);
        bv[i] = *(const bf16x8*)(Bt + (wn + i * 16 + (lane & 15)) * 64 + kb);
      }
      #pragma unroll
      for(int i = 0; i < 4; i++)
        #pragma unroll
        for(int j = 0; j < 4; j++)
          acc[i][j] = __builtin_amdgcn_mfma_f32_16x16x32_bf16(af[i], bv[j], acc[i][j], 0, 0, 0);
    }
  }
  const int r0 = m0 + wm + ((lane >> 4) << 2);
  const int c0 = n0 + wn + (lane & 15);
  #pragma unroll
  for(int i = 0; i < 4; i++)
    #pragma unroll
    for(int j = 0; j < 4; j++)
      #pragma unroll
      for(int r = 0; r < 4; r++)
        Ct[(size_t)(r0 + i * 16 + r) * DD + c0 + j * 16] = f2bf(fast_tanh(acc[i][j][r]));
}

// ---------- gemmB: scores = W_p2 . relu(tanh_buf @ W_p1a^T + bias2) + b_p2 ----------
__global__ __launch_bounds__(256) void gemmB_kernel(
    const unsigned short* __restrict__ A, const unsigned short* __restrict__ B,
    const float* __restrict__ bias2, const float* __restrict__ w2,
    const float* __restrict__ bp2, float* __restrict__ scores)
{
  __shared__ unsigned short At[64 * 64];     // 8 KB
  __shared__ unsigned short Bt[256 * 64];    // 32 KB
  __shared__ float sred[4][64];
  const int tid = threadIdx.x, lane = tid & 63, w = tid >> 6;
  const int m0 = blockIdx.x * 64;
  f32x4 acc[4][4] = {};
  for(int kt = 0; kt < DD; kt += 64){
    __syncthreads();
    #pragma unroll
    for(int i = 0; i < 2; i++){
      int off = (w * 2 + i) * 1024 + lane * 16;
      int row = off >> 7, cb = off & 127;
      gl_lds16(A + (size_t)(m0 + row) * DD + kt + (cb >> 1), (char*)At + (w * 2 + i) * 1024);
    }
    #pragma unroll
    for(int i = 0; i < 8; i++){
      int off = (w * 8 + i) * 1024 + lane * 16;
      int row = off >> 7, cb = off & 127;
      gl_lds16(B + (size_t)row * DD + kt + (cb >> 1), (char*)Bt + (w * 8 + i) * 1024);
    }
    __syncthreads();
    #pragma unroll
    for(int ks = 0; ks < 2; ks++){
      const int kb = ks * 32 + (lane >> 4) * 8;
      bf16x8 af[4], bv[4];
      #pragma unroll
      for(int i = 0; i < 4; i++){
        af[i] = *(const bf16x8*)(At + (i * 16 + (lane & 15)) * 64 + kb);
        bv[i] = *(const bf16x8*)(Bt + (w * 64 + i * 16 + (lane & 15)) * 64 + kb);
      }
      #pragma unroll
      for(int i = 0; i < 4; i++)
        #pragma unroll
        for(int j = 0; j < 4; j++)
          acc[i][j] = __builtin_amdgcn_mfma_f32_16x16x32_bf16(af[i], bv[j], acc[i][j], 0, 0, 0);
    }
  }
  float w2v[4], b2v[4];
  #pragma unroll
  for(int in = 0; in < 4; in++){
    int n = w * 64 + in * 16 + (lane & 15);
    w2v[in] = (n < HH) ? w2[n] : 0.f;
    b2v[in] = bias2[n];
  }
  #pragma unroll
  for(int im = 0; im < 4; im++){
    #pragma unroll
    for(int r = 0; r < 4; r++){
      float s = 0.f;
      #pragma unroll
      for(int in = 0; in < 4; in++){
        float h = acc[im][in][r] + b2v[in];
        s += (h > 0.f ? h : 0.f) * w2v[in];
      }
      s += __shfl_xor(s, 1); s += __shfl_xor(s, 2);
      s += __shfl_xor(s, 4); s += __shfl_xor(s, 8);
      if((lane & 15) == 0) sred[w][im * 16 + (lane >> 4) * 4 + r] = s;
    }
  }
  __syncthreads();
  if(tid < 64)
    scores[m0 + tid] = sred[0][tid] + sred[1][tid] + sred[2][tid] + sred[3][tid] + bp2[0];
}

// ---------- masked softmax ----------
__global__ __launch_bounds__(1024) void softmax_kernel(
    const float* __restrict__ scores, const int* __restrict__ mask, float* __restrict__ attn)
{
  __shared__ float red[16];
  const int tid = threadIdx.x;
  float m = -3.0e38f;
  for(int i = tid; i < SS; i += 1024) if(mask[i] == 0) m = fmaxf(m, scores[i]);
  #pragma unroll
  for(int o = 32; o; o >>= 1) m = fmaxf(m, __shfl_xor(m, o));
  if((tid & 63) == 0) red[tid >> 6] = m;
  __syncthreads();
  float M = -3.0e38f;
  #pragma unroll
  for(int i = 0; i < 16; i++) M = fmaxf(M, red[i]);
  __syncthreads();
  float s = 0.f;
  for(int i = tid; i < SS; i += 1024) if(mask[i] == 0) s += __expf(scores[i] - M);
  #pragma unroll
  for(int o = 32; o; o >>= 1) s += __shfl_xor(s, o);
  if((tid & 63) == 0) red[tid >> 6] = s;
  __syncthreads();
  float T = 0.f;
  #pragma unroll
  for(int i = 0; i < 16; i++) T += red[i];
  const float inv = 1.0f / T;
  for(int i = tid; i < SS; i += 1024)
    attn[i] = (mask[i] == 0) ? __expf(scores[i] - M) * inv : 0.f;
}

// ---------- ctx = attn @ enc ----------
__global__ __launch_bounds__(256) void ctxp_kernel(
    const float* __restrict__ attn, const float* __restrict__ enc, float* __restrict__ part)
{
  const int b = blockIdx.x, t = threadIdx.x;
  float a0=0,a1=0,a2=0,a3=0,a4=0,a5=0,a6=0,a7=0;
  const float* base = enc + (size_t)b * 256 * DD + t * 8;
  const float* ap = attn + b * 256;
  for(int s = 0; s < 256; s++){
    float av = ap[s];
    const float4* p = (const float4*)(base + (size_t)s * DD);
    float4 x = p[0], y = p[1];
    a0 += av * x.x; a1 += av * x.y; a2 += av * x.z; a3 += av * x.w;
    a4 += av * y.x; a5 += av * y.y; a6 += av * y.z; a7 += av * y.w;
  }
  float* o = part + (size_t)b * DD + t * 8;
  o[0]=a0; o[1]=a1; o[2]=a2; o[3]=a3; o[4]=a4; o[5]=a5; o[6]=a6; o[7]=a7;
}

__global__ void ctxr_kernel(const float* __restrict__ part, float* __restrict__ out){
  const int d = blockIdx.x * 256 + threadIdx.x;
  float s = 0.f;
  for(int b = 0; b < 64; b++) s += part[(size_t)b * DD + d];
  out[d] = s;
}

// ---------- launch ----------
extern "C" void kernel_launch(void* const* d_in, const int* in_sizes, int n_in,
                              void* d_out, int out_size, void* d_ws, size_t ws_size,
                              hipStream_t stream)
{
  const float* s_prev = (const float*)d_in[0];
  const float* enc    = (const float*)d_in[1];
  const float* cmr    = (const float*)d_in[2];
  const int*   mask   = (const int*)d_in[3];
  const float* W_info = (const float*)d_in[4];
  const float* W_ctx  = (const float*)d_in[5];
  const float* W_q    = (const float*)d_in[6];
  const float* b_q    = (const float*)d_in[7];
  const float* W_p1   = (const float*)d_in[8];
  const float* b_p1   = (const float*)d_in[9];
  const float* W_p2   = (const float*)d_in[10];
  const float* b_p2   = (const float*)d_in[11];
  float* out = (float*)d_out;

  char* ws = (char*)d_ws;
  unsigned short* tanhbuf = (unsigned short*)(ws);                   // 67108864 B
  unsigned short* wctxb   = (unsigned short*)(ws + 67108864);        //  8388608 B
  unsigned short* wp1ab   = (unsigned short*)(ws + 75497472);        //  1048576 B
  float* twq    = (float*)(ws + 76546048);                           //     8192 B
  float* tdh    = (float*)(ws + 76554240);                           //     8192 B
  float* bias2  = (float*)(ws + 76562432);                           //     1024 B
  float* scores = (float*)(ws + 76563456);                           //    65536 B
  float* part   = (float*)(ws + 76628992);                           //   524288 B

  conv_wctx_kernel<<<512, 256, 0, stream>>>(W_ctx, wctxb);
  conv_wp1a_kernel<<<256, 256, 0, stream>>>(W_p1, wp1ab);
  vec_kernel<<<1024, 256, 0, stream>>>(s_prev, cmr, W_q, b_q, W_info, twq, tdh);
  bias2_kernel<<<64, 256, 0, stream>>>(W_p1, b_p1, twq, tdh, bias2);
  gemmA_kernel<<<dim3(16, 128), 256, 0, stream>>>(enc, wctxb, tanhbuf);
  gemmB_kernel<<<256, 256, 0, stream>>>(tanhbuf, wp1ab, bias2, W_p2, b_p2, scores);
  softmax_kernel<<<1, 1024, 0, stream>>>(scores, mask, out);
  ctxp_kernel<<<64, 256, 0, stream>>>(out, enc, part);
  ctxr_kernel<<<8, 256, 0, stream>>>(part, out + SS);
}

// Round 2
// 241.656 us; speedup vs baseline: 1.6361x; 1.6361x over previous
//
#include <hip/hip_runtime.h>
#include <hip/hip_bf16.h>
#include <stdint.h>

#define DD 2048
#define SS 16384
#define HH 250

typedef __attribute__((ext_vector_type(8))) short bf16x8;
typedef __attribute__((ext_vector_type(4))) short bf16x4;
typedef __attribute__((ext_vector_type(4))) float f32x4;

__device__ __forceinline__ unsigned short f2bf(float f){
  union { float f; uint32_t u; } v; v.f = f;
  uint32_t u = v.u;
  return (unsigned short)((u + 0x7fffu + ((u >> 16) & 1u)) >> 16);
}
__device__ __forceinline__ float fast_tanh(float x){
  return 1.0f - 2.0f / (1.0f + __expf(2.0f * x));
}
__device__ __forceinline__ void gl_lds16(const void* g, void* l){
  __builtin_amdgcn_global_load_lds((const __attribute__((address_space(1))) void*)g,
                                   (__attribute__((address_space(3))) void*)l, 16, 0, 0);
}

// ---------- mask scan -> compacted row index list ----------
__global__ __launch_bounds__(1024) void scan_kernel(const int* __restrict__ mask,
                                                    int* __restrict__ idx,
                                                    int* __restrict__ mcount)
{
  __shared__ int cnt[1024];
  const int t = threadIdx.x;
  const int base = t * 16;
  int loc[16];
  int c = 0;
  #pragma unroll
  for(int i = 0; i < 16; i++){ loc[i] = (mask[base + i] == 0); c += loc[i]; }
  cnt[t] = c;
  __syncthreads();
  for(int off = 1; off < 1024; off <<= 1){
    int v = (t >= off) ? cnt[t - off] : 0;
    __syncthreads();
    cnt[t] += v;
    __syncthreads();
  }
  int p = cnt[t] - c;          // exclusive prefix
  #pragma unroll
  for(int i = 0; i < 16; i++) if(loc[i]) idx[p++] = base + i;
  if(t == 1023){
    int total = cnt[1023];
    mcount[0] = total;
    mcount[1] = (total + 127) & ~127;   // padded to tile multiple
  }
}

// ---------- compacted enc f32 -> bf16 (one row per block) ----------
__global__ __launch_bounds__(256) void conv_enc_kernel(
    const float* __restrict__ enc, const int* __restrict__ idx,
    const int* __restrict__ mcount, unsigned short* __restrict__ out)
{
  const int j = blockIdx.x;
  if(j >= mcount[1]) return;
  const int t = threadIdx.x;
  unsigned short* o = out + (size_t)j * DD + t * 8;
  if(j >= mcount[0]){
    bf16x8 z;
    #pragma unroll
    for(int i = 0; i < 8; i++) z[i] = 0;
    *(bf16x8*)o = z;
    return;
  }
  const float* s = enc + (size_t)idx[j] * DD + t * 8;
  const float4* p = (const float4*)s;
  float4 a = p[0], b = p[1];
  bf16x8 v;
  v[0]=(short)f2bf(a.x); v[1]=(short)f2bf(a.y); v[2]=(short)f2bf(a.z); v[3]=(short)f2bf(a.w);
  v[4]=(short)f2bf(b.x); v[5]=(short)f2bf(b.y); v[6]=(short)f2bf(b.z); v[7]=(short)f2bf(b.w);
  *(bf16x8*)o = v;
}

// ---------- weight converts ----------
__global__ void conv_wctx_kernel(const float* __restrict__ w, unsigned short* __restrict__ o){
  const int n8 = (DD * DD) / 8;
  for(int i = blockIdx.x * 256 + threadIdx.x; i < n8; i += gridDim.x * 256){
    const float4* p = (const float4*)(w + (size_t)i * 8);
    float4 a = p[0], b = p[1];
    bf16x8 v;
    v[0]=(short)f2bf(a.x); v[1]=(short)f2bf(a.y); v[2]=(short)f2bf(a.z); v[3]=(short)f2bf(a.w);
    v[4]=(short)f2bf(b.x); v[5]=(short)f2bf(b.y); v[6]=(short)f2bf(b.z); v[7]=(short)f2bf(b.w);
    *(bf16x8*)(o + (size_t)i * 8) = v;
  }
}

__global__ void conv_wp1a_kernel(const float* __restrict__ w, unsigned short* __restrict__ o){
  int g = blockIdx.x * 256 + threadIdx.x;      // [256][2048] bf16, rows >= HH zero
  int row = g >> 8, col = (g & 255) * 8;
  const float* s = w + (size_t)row * (3 * DD) + col;
  bf16x8 v;
  #pragma unroll
  for(int j = 0; j < 8; j++) v[j] = (row < HH) ? (short)f2bf(s[j]) : (short)0;
  *(bf16x8*)(o + (size_t)g * 8) = v;
}

// ---------- small precompute ----------
__global__ void vec_kernel(const float* __restrict__ s_prev, const float* __restrict__ cmr,
                           const float* __restrict__ Wq, const float* __restrict__ bq,
                           const float* __restrict__ Winfo,
                           float* __restrict__ twq, float* __restrict__ tdh)
{
  int wid = threadIdx.x >> 6, lane = threadIdx.x & 63;
  bool isq = blockIdx.x < 512;
  int r = (isq ? blockIdx.x : blockIdx.x - 512) * 4 + wid;
  const float* M = (isq ? Wq : Winfo) + (size_t)r * DD;
  const float* x = isq ? s_prev : cmr;
  float s = 0.f;
  for(int i = lane; i < DD; i += 64) s += M[i] * x[i];
  #pragma unroll
  for(int o = 32; o; o >>= 1) s += __shfl_xor(s, o);
  if(lane == 0){
    if(isq) twq[r] = fast_tanh(s + bq[r]);
    else    tdh[r] = fast_tanh(s);
  }
}

__global__ void bias2_kernel(const float* __restrict__ wp1, const float* __restrict__ bp1,
                             const float* __restrict__ twq, const float* __restrict__ tdh,
                             float* __restrict__ bias2)
{
  int h = blockIdx.x * 4 + (threadIdx.x >> 6);
  int lane = threadIdx.x & 63;
  if(h >= HH){ if(lane == 0) bias2[h] = 0.f; return; }
  const float* r1 = wp1 + (size_t)h * (3 * DD) + DD;
  const float* r2 = wp1 + (size_t)h * (3 * DD) + 2 * DD;
  float s = 0.f;
  for(int i = lane; i < DD; i += 64) s += r1[i] * twq[i] + r2[i] * tdh[i];
  #pragma unroll
  for(int o = 32; o; o >>= 1) s += __shfl_xor(s, o);
  if(lane == 0) bias2[h] = s + bp1[h];
}

// ---------- gemmA: tanh(encb @ W_ctx^T) -> bf16, compacted rows ----------
__global__ __launch_bounds__(256) void gemmA_kernel(
    const unsigned short* __restrict__ A, const unsigned short* __restrict__ B,
    const int* __restrict__ mcount, unsigned short* __restrict__ Ct)
{
  __shared__ unsigned short At[128 * 64];   // 16 KB, st_16x32-style swizzled
  __shared__ unsigned short Bt[128 * 64];   // 16 KB
  const int tid = threadIdx.x, lane = tid & 63, w = tid >> 6;
  const int n0 = blockIdx.x * 128, m0 = blockIdx.y * 128;
  if(m0 >= mcount[1]) return;
  const int wm = (w >> 1) * 64, wn = (w & 1) * 64;
  // pre-swizzled global source: lane l stages row (l>>3), col-bytes 16*((l&7)^(l>>3))
  const int srow = lane >> 3;
  const int scol = ((lane & 7) ^ srow) * 16;
  const int xorv = (lane & 7) << 4;         // ds_read swizzle term (row&7 == lane&7)

  f32x4 acc[4][4] = {};

  for(int kt = 0; kt < DD; kt += 64){
    __syncthreads();
    #pragma unroll
    for(int i = 0; i < 4; i++){
      int r8 = (w * 4 + i) * 8;
      gl_lds16((const char*)(A + (size_t)(m0 + r8 + srow) * DD + kt) + scol,
               (char*)At + r8 * 128);
      gl_lds16((const char*)(B + (size_t)(n0 + r8 + srow) * DD + kt) + scol,
               (char*)Bt + r8 * 128);
    }
    __syncthreads();
    #pragma unroll
    for(int ks = 0; ks < 2; ks++){
      const int cb = (ks * 4 + (lane >> 4)) * 16;      // chunk byte within row
      bf16x8 af[4], bv[4];
      #pragma unroll
      for(int i = 0; i < 4; i++){
        af[i] = *(const bf16x8*)((const char*)At + (wm + i * 16 + (lane & 15)) * 128 + (cb ^ xorv));
        bv[i] = *(const bf16x8*)((const char*)Bt + (wn + i * 16 + (lane & 15)) * 128 + (cb ^ xorv));
      }
      #pragma unroll
      for(int i = 0; i < 4; i++)
        #pragma unroll
        for(int j = 0; j < 4; j++)
          acc[i][j] = __builtin_amdgcn_mfma_f32_16x16x32_bf16(af[i], bv[j], acc[i][j], 0, 0, 0);
    }
  }
  const int r0 = m0 + wm + ((lane >> 4) << 2);
  const int c0 = n0 + wn + (lane & 15);
  #pragma unroll
  for(int i = 0; i < 4; i++)
    #pragma unroll
    for(int j = 0; j < 4; j++)
      #pragma unroll
      for(int r = 0; r < 4; r++)
        Ct[(size_t)(r0 + i * 16 + r) * DD + c0 + j * 16] = f2bf(fast_tanh(acc[i][j][r]));
}

// ---------- gemmB: scores_c = W_p2 . relu(tanh_buf @ W_p1a^T + bias2) + b_p2 ----------
__global__ __launch_bounds__(256) void gemmB_kernel(
    const unsigned short* __restrict__ A, const unsigned short* __restrict__ B,
    const int* __restrict__ mcount, const float* __restrict__ bias2,
    const float* __restrict__ w2, const float* __restrict__ bp2,
    float* __restrict__ scores)
{
  __shared__ unsigned short At[64 * 64];     // 8 KB
  __shared__ unsigned short Bt[256 * 64];    // 32 KB
  __shared__ float sred[4][64];
  const int tid = threadIdx.x, lane = tid & 63, w = tid >> 6;
  const int m0 = blockIdx.x * 64;
  if(m0 >= mcount[1]) return;
  const int srow = lane >> 3;
  const int scol = ((lane & 7) ^ srow) * 16;
  const int xorv = (lane & 7) << 4;
  f32x4 acc[4][4] = {};
  for(int kt = 0; kt < DD; kt += 64){
    __syncthreads();
    #pragma unroll
    for(int i = 0; i < 2; i++){
      int r8 = (w * 2 + i) * 8;
      gl_lds16((const char*)(A + (size_t)(m0 + r8 + srow) * DD + kt) + scol,
               (char*)At + r8 * 128);
    }
    #pragma unroll
    for(int i = 0; i < 8; i++){
      int r8 = (w * 8 + i) * 8;
      gl_lds16((const char*)(B + (size_t)(r8 + srow) * DD + kt) + scol,
               (char*)Bt + r8 * 128);
    }
    __syncthreads();
    #pragma unroll
    for(int ks = 0; ks < 2; ks++){
      const int cb = (ks * 4 + (lane >> 4)) * 16;
      bf16x8 af[4], bv[4];
      #pragma unroll
      for(int i = 0; i < 4; i++){
        af[i] = *(const bf16x8*)((const char*)At + (i * 16 + (lane & 15)) * 128 + (cb ^ xorv));
        bv[i] = *(const bf16x8*)((const char*)Bt + (w * 64 + i * 16 + (lane & 15)) * 128 + (cb ^ xorv));
      }
      #pragma unroll
      for(int i = 0; i < 4; i++)
        #pragma unroll
        for(int j = 0; j < 4; j++)
          acc[i][j] = __builtin_amdgcn_mfma_f32_16x16x32_bf16(af[i], bv[j], acc[i][j], 0, 0, 0);
    }
  }
  float w2v[4], b2v[4];
  #pragma unroll
  for(int in = 0; in < 4; in++){
    int n = w * 64 + in * 16 + (lane & 15);
    w2v[in] = (n < HH) ? w2[n] : 0.f;
    b2v[in] = bias2[n];
  }
  #pragma unroll
  for(int im = 0; im < 4; im++){
    #pragma unroll
    for(int r = 0; r < 4; r++){
      float s = 0.f;
      #pragma unroll
      for(int in = 0; in < 4; in++){
        float h = acc[im][in][r] + b2v[in];
        s += (h > 0.f ? h : 0.f) * w2v[in];
      }
      s += __shfl_xor(s, 1); s += __shfl_xor(s, 2);
      s += __shfl_xor(s, 4); s += __shfl_xor(s, 8);
      if((lane & 15) == 0) sred[w][im * 16 + (lane >> 4) * 4 + r] = s;
    }
  }
  __syncthreads();
  if(tid < 64)
    scores[m0 + tid] = sred[0][tid] + sred[1][tid] + sred[2][tid] + sred[3][tid] + bp2[0];
}

// ---------- scatter compacted scores back to full index space ----------
__global__ void scatter_kernel(const float* __restrict__ sc, const int* __restrict__ idx,
                               const int* __restrict__ mcount, float* __restrict__ sf)
{
  int j = blockIdx.x * 256 + threadIdx.x;
  if(j < mcount[0]) sf[idx[j]] = sc[j];
}

// ---------- masked softmax ----------
__global__ __launch_bounds__(1024) void softmax_kernel(
    const float* __restrict__ scores, const int* __restrict__ mask, float* __restrict__ attn)
{
  __shared__ float red[16];
  const int tid = threadIdx.x;
  float m = -3.0e38f;
  for(int i = tid; i < SS; i += 1024) if(mask[i] == 0) m = fmaxf(m, scores[i]);
  #pragma unroll
  for(int o = 32; o; o >>= 1) m = fmaxf(m, __shfl_xor(m, o));
  if((tid & 63) == 0) red[tid >> 6] = m;
  __syncthreads();
  float M = -3.0e38f;
  #pragma unroll
  for(int i = 0; i < 16; i++) M = fmaxf(M, red[i]);
  __syncthreads();
  float s = 0.f;
  for(int i = tid; i < SS; i += 1024) if(mask[i] == 0) s += __expf(scores[i] - M);
  #pragma unroll
  for(int o = 32; o; o >>= 1) s += __shfl_xor(s, o);
  if((tid & 63) == 0) red[tid >> 6] = s;
  __syncthreads();
  float T = 0.f;
  #pragma unroll
  for(int i = 0; i < 16; i++) T += red[i];
  const float inv = 1.0f / T;
  for(int i = tid; i < SS; i += 1024)
    attn[i] = (mask[i] == 0) ? __expf(scores[i] - M) * inv : 0.f;
}

// ---------- ctx = attn @ enc (512 blocks, skip attn==0 rows) ----------
__global__ __launch_bounds__(256) void ctxp_kernel(
    const float* __restrict__ attn, const float* __restrict__ enc, float* __restrict__ part)
{
  const int b = blockIdx.x, t = threadIdx.x;
  float a0=0,a1=0,a2=0,a3=0,a4=0,a5=0,a6=0,a7=0;
  const float* base = enc + (size_t)b * 32 * DD + t * 8;
  const float* ap = attn + b * 32;
  for(int s = 0; s < 32; s++){
    float av = ap[s];
    if(av != 0.f){
      const float4* p = (const float4*)(base + (size_t)s * DD);
      float4 x = p[0], y = p[1];
      a0 += av * x.x; a1 += av * x.y; a2 += av * x.z; a3 += av * x.w;
      a4 += av * y.x; a5 += av * y.y; a6 += av * y.z; a7 += av * y.w;
    }
  }
  float* o = part + (size_t)b * DD + t * 8;
  o[0]=a0; o[1]=a1; o[2]=a2; o[3]=a3; o[4]=a4; o[5]=a5; o[6]=a6; o[7]=a7;
}

__global__ void ctxr_kernel(const float* __restrict__ part, float* __restrict__ out){
  const int d = blockIdx.x * 256 + threadIdx.x;
  float s = 0.f;
  for(int b = 0; b < 512; b++) s += part[(size_t)b * DD + d];
  out[d] = s;
}

// ---------- launch ----------
extern "C" void kernel_launch(void* const* d_in, const int* in_sizes, int n_in,
                              void* d_out, int out_size, void* d_ws, size_t ws_size,
                              hipStream_t stream)
{
  const float* s_prev = (const float*)d_in[0];
  const float* enc    = (const float*)d_in[1];
  const float* cmr    = (const float*)d_in[2];
  const int*   mask   = (const int*)d_in[3];
  const float* W_info = (const float*)d_in[4];
  const float* W_ctx  = (const float*)d_in[5];
  const float* W_q    = (const float*)d_in[6];
  const float* b_q    = (const float*)d_in[7];
  const float* W_p1   = (const float*)d_in[8];
  const float* b_p1   = (const float*)d_in[9];
  const float* W_p2   = (const float*)d_in[10];
  const float* b_p2   = (const float*)d_in[11];
  float* out = (float*)d_out;

  char* ws = (char*)d_ws;
  unsigned short* encb    = (unsigned short*)(ws);                   // 67108864 B
  unsigned short* tanhbuf = (unsigned short*)(ws + 67108864);        // 67108864 B
  unsigned short* wctxb   = (unsigned short*)(ws + 134217728);       //  8388608 B
  unsigned short* wp1ab   = (unsigned short*)(ws + 142606336);       //  1048576 B
  int*   idx     = (int*)(ws + 143654912);                           //    65536 B
  float* scoresc = (float*)(ws + 143720448);                         //    65536 B
  float* scoresf = (float*)(ws + 143785984);                         //    65536 B
  float* twq     = (float*)(ws + 143851520);                         //     8192 B
  float* tdh     = (float*)(ws + 143859712);                         //     8192 B
  float* bias2   = (float*)(ws + 143867904);                         //     1024 B
  int*   mcount  = (int*)(ws + 143868928);                           //      256 B
  float* part    = (float*)(ws);   // aliases encb (dead after gemmA)

  scan_kernel<<<1, 1024, 0, stream>>>(mask, idx, mcount);
  conv_enc_kernel<<<16384, 256, 0, stream>>>(enc, idx, mcount, encb);
  conv_wctx_kernel<<<512, 256, 0, stream>>>(W_ctx, wctxb);
  conv_wp1a_kernel<<<256, 256, 0, stream>>>(W_p1, wp1ab);
  vec_kernel<<<1024, 256, 0, stream>>>(s_prev, cmr, W_q, b_q, W_info, twq, tdh);
  bias2_kernel<<<64, 256, 0, stream>>>(W_p1, b_p1, twq, tdh, bias2);
  gemmA_kernel<<<dim3(16, 128), 256, 0, stream>>>(encb, wctxb, mcount, tanhbuf);
  gemmB_kernel<<<256, 256, 0, stream>>>(tanhbuf, wp1ab, mcount, bias2, W_p2, b_p2, scoresc);
  scatter_kernel<<<64, 256, 0, stream>>>(scoresc, idx, mcount, scoresf);
  softmax_kernel<<<1, 1024, 0, stream>>>(scoresf, mask, out);
  ctxp_kernel<<<512, 256, 0, stream>>>(out, enc, part);
  ctxr_kernel<<<8, 256, 0, stream>>>(part, out + SS);
}

// Round 3
// 222.118 us; speedup vs baseline: 1.7800x; 1.0880x over previous
//
#include <hip/hip_runtime.h>
#include <hip/hip_bf16.h>
#include <stdint.h>

#define DD 2048
#define SS 16384
#define HH 250

typedef __attribute__((ext_vector_type(8))) short bf16x8;
typedef __attribute__((ext_vector_type(4))) short bf16x4;
typedef __attribute__((ext_vector_type(4))) float f32x4;

__device__ __forceinline__ unsigned short f2bf(float f){
  union { float f; uint32_t u; } v; v.f = f;
  uint32_t u = v.u;
  return (unsigned short)((u + 0x7fffu + ((u >> 16) & 1u)) >> 16);
}
__device__ __forceinline__ float fast_tanh(float x){
  return 1.0f - 2.0f / (1.0f + __expf(2.0f * x));
}
__device__ __forceinline__ void gl_lds16(const void* g, void* l){
  __builtin_amdgcn_global_load_lds((const __attribute__((address_space(1))) void*)g,
                                   (__attribute__((address_space(3))) void*)l, 16, 0, 0);
}

// ---------- mask scan -> compacted row index list ----------
__global__ __launch_bounds__(1024) void scan_kernel(const int* __restrict__ mask,
                                                    int* __restrict__ idx,
                                                    int* __restrict__ mcount)
{
  __shared__ int cnt[1024];
  const int t = threadIdx.x;
  const int base = t * 16;
  int loc[16];
  int c = 0;
  #pragma unroll
  for(int i = 0; i < 16; i++){ loc[i] = (mask[base + i] == 0); c += loc[i]; }
  cnt[t] = c;
  __syncthreads();
  for(int off = 1; off < 1024; off <<= 1){
    int v = (t >= off) ? cnt[t - off] : 0;
    __syncthreads();
    cnt[t] += v;
    __syncthreads();
  }
  int p = cnt[t] - c;          // exclusive prefix
  #pragma unroll
  for(int i = 0; i < 16; i++) if(loc[i]) idx[p++] = base + i;
  if(t == 1023){
    int total = cnt[1023];
    mcount[0] = total;
    mcount[1] = (total + 255) & ~255;   // padded to 256-row tile multiple
  }
}

// ---------- compacted enc f32 -> bf16 (one row per block) ----------
__global__ __launch_bounds__(256) void conv_enc_kernel(
    const float* __restrict__ enc, const int* __restrict__ idx,
    const int* __restrict__ mcount, unsigned short* __restrict__ out)
{
  const int j = blockIdx.x;
  if(j >= mcount[1]) return;
  const int t = threadIdx.x;
  unsigned short* o = out + (size_t)j * DD + t * 8;
  if(j >= mcount[0]){
    bf16x8 z;
    #pragma unroll
    for(int i = 0; i < 8; i++) z[i] = 0;
    *(bf16x8*)o = z;
    return;
  }
  const float* s = enc + (size_t)idx[j] * DD + t * 8;
  const float4* p = (const float4*)s;
  float4 a = p[0], b = p[1];
  bf16x8 v;
  v[0]=(short)f2bf(a.x); v[1]=(short)f2bf(a.y); v[2]=(short)f2bf(a.z); v[3]=(short)f2bf(a.w);
  v[4]=(short)f2bf(b.x); v[5]=(short)f2bf(b.y); v[6]=(short)f2bf(b.z); v[7]=(short)f2bf(b.w);
  *(bf16x8*)o = v;
}

// ---------- weight converts ----------
__global__ void conv_wctx_kernel(const float* __restrict__ w, unsigned short* __restrict__ o){
  const int n8 = (DD * DD) / 8;
  for(int i = blockIdx.x * 256 + threadIdx.x; i < n8; i += gridDim.x * 256){
    const float4* p = (const float4*)(w + (size_t)i * 8);
    float4 a = p[0], b = p[1];
    bf16x8 v;
    v[0]=(short)f2bf(a.x); v[1]=(short)f2bf(a.y); v[2]=(short)f2bf(a.z); v[3]=(short)f2bf(a.w);
    v[4]=(short)f2bf(b.x); v[5]=(short)f2bf(b.y); v[6]=(short)f2bf(b.z); v[7]=(short)f2bf(b.w);
    *(bf16x8*)(o + (size_t)i * 8) = v;
  }
}

__global__ void conv_wp1a_kernel(const float* __restrict__ w, unsigned short* __restrict__ o){
  int g = blockIdx.x * 256 + threadIdx.x;      // [256][2048] bf16, rows >= HH zero
  int row = g >> 8, col = (g & 255) * 8;
  const float* s = w + (size_t)row * (3 * DD) + col;
  bf16x8 v;
  #pragma unroll
  for(int j = 0; j < 8; j++) v[j] = (row < HH) ? (short)f2bf(s[j]) : (short)0;
  *(bf16x8*)(o + (size_t)g * 8) = v;
}

// ---------- small precompute ----------
__global__ void vec_kernel(const float* __restrict__ s_prev, const float* __restrict__ cmr,
                           const float* __restrict__ Wq, const float* __restrict__ bq,
                           const float* __restrict__ Winfo,
                           float* __restrict__ twq, float* __restrict__ tdh)
{
  int wid = threadIdx.x >> 6, lane = threadIdx.x & 63;
  bool isq = blockIdx.x < 512;
  int r = (isq ? blockIdx.x : blockIdx.x - 512) * 4 + wid;
  const float* M = (isq ? Wq : Winfo) + (size_t)r * DD;
  const float* x = isq ? s_prev : cmr;
  float s = 0.f;
  for(int i = lane; i < DD; i += 64) s += M[i] * x[i];
  #pragma unroll
  for(int o = 32; o; o >>= 1) s += __shfl_xor(s, o);
  if(lane == 0){
    if(isq) twq[r] = fast_tanh(s + bq[r]);
    else    tdh[r] = fast_tanh(s);
  }
}

__global__ void bias2_kernel(const float* __restrict__ wp1, const float* __restrict__ bp1,
                             const float* __restrict__ twq, const float* __restrict__ tdh,
                             float* __restrict__ bias2)
{
  int h = blockIdx.x * 4 + (threadIdx.x >> 6);
  int lane = threadIdx.x & 63;
  if(h >= HH){ if(lane == 0) bias2[h] = 0.f; return; }
  const float* r1 = wp1 + (size_t)h * (3 * DD) + DD;
  const float* r2 = wp1 + (size_t)h * (3 * DD) + 2 * DD;
  float s = 0.f;
  for(int i = lane; i < DD; i += 64) s += r1[i] * twq[i] + r2[i] * tdh[i];
  #pragma unroll
  for(int o = 32; o; o >>= 1) s += __shfl_xor(s, o);
  if(lane == 0) bias2[h] = s + bp1[h];
}

// ---------- gemmA: 256x256 8-phase schedule (T2+T3+T4+T5) ----------
// stage one 128-row x 64-col bf16 half-tile: 8 waves x 2 gl_lds16 (1KB each)
// global source pre-swizzled so linear LDS dest + XOR'd ds_read line up (rule #21)
__device__ __forceinline__ void stage_half(const unsigned short* __restrict__ g,
                                           int grow0, int kt, char* ldsbase,
                                           int wid, int lane)
{
  const int srow = lane >> 3;
  const int c = (lane & 7) ^ srow;
  #pragma unroll
  for(int i = 0; i < 2; i++){
    int r8 = (wid * 2 + i) * 8;
    gl_lds16((const char*)(g + (size_t)(grow0 + r8 + srow) * DD + kt) + c * 16,
             ldsbase + r8 * 128);
  }
}

__global__ __launch_bounds__(512, 2) void gemmA_kernel(
    const unsigned short* __restrict__ A, const unsigned short* __restrict__ B,
    const int* __restrict__ mcount, unsigned short* __restrict__ Ct)
{
  __shared__ alignas(128) char lds[131072];   // 2 bufs x (A 32KB + B 32KB)
  const int tid = threadIdx.x, lane = tid & 63, wid = tid >> 6;
  const int wm = wid >> 2, wn = wid & 3;          // 2M x 4N waves
  const int m0 = (blockIdx.x >> 3) * 256, n0 = (blockIdx.x & 7) * 256;
  if(m0 >= mcount[1]) return;
  const int frow = lane & 15, kch = lane >> 4;

  f32x4 acc[8][4] = {};

  // prologue: tile0 (A h0,h1,B h0,h1) + tile1 B h0,h1 ; wait tile0 (8 loads)
  stage_half(A, m0,        0, lds,                 wid, lane);
  stage_half(A, m0 + 128,  0, lds + 16384,         wid, lane);
  stage_half(B, n0,        0, lds + 32768,         wid, lane);
  stage_half(B, n0 + 128,  0, lds + 49152,         wid, lane);
  stage_half(B, n0,       64, lds + 65536 + 32768, wid, lane);
  stage_half(B, n0 + 128, 64, lds + 65536 + 49152, wid, lane);
  asm volatile("s_waitcnt vmcnt(4)" ::: "memory");
  __builtin_amdgcn_s_barrier();

  #pragma unroll 2
  for(int t = 0; t < 32; t++){
    const int d = t & 1;
    char* Ab = lds + d * 65536;
    char* Bb = Ab + 32768;
    char* An = lds + (d ^ 1) * 65536;
    bf16x8 bfr[4][2];
    #pragma unroll
    for(int q = 0; q < 4; q++){
      // ---- ds-reads for this phase (current buffer) ----
      if(q == 0){
        #pragma unroll
        for(int nr = 0; nr < 4; nr++){
          int row = wn * 64 + nr * 16 + frow;
          int xo = (row & 7) << 4;
          #pragma unroll
          for(int ks = 0; ks < 2; ks++)
            bfr[nr][ks] = *(const bf16x8*)(Bb + row * 128 + (((ks * 4 + kch) * 16) ^ xo));
        }
      }
      bf16x8 afr[2][2];
      #pragma unroll
      for(int mi = 0; mi < 2; mi++){
        int row = wm * 128 + (q * 2 + mi) * 16 + frow;
        int xo = (row & 7) << 4;
        #pragma unroll
        for(int ks = 0; ks < 2; ks++)
          afr[mi][ks] = *(const bf16x8*)(Ab + row * 128 + (((ks * 4 + kch) * 16) ^ xo));
      }
      // ---- stage issues (counted, never drained mid-loop) ----
      if(q == 0){
        if(t + 1 < 32){
          stage_half(A, m0,       (t + 1) * 64, An,         wid, lane);
          stage_half(A, m0 + 128, (t + 1) * 64, An + 16384, wid, lane);
        }
      } else if(q == 1){
        if(t + 2 < 32) stage_half(B, n0,       (t + 2) * 64, Bb,         wid, lane);
      } else if(q == 2){
        if(t + 2 < 32) stage_half(B, n0 + 128, (t + 2) * 64, Bb + 16384, wid, lane);
      }
      __builtin_amdgcn_s_barrier();
      __builtin_amdgcn_sched_barrier(0);
      __builtin_amdgcn_s_setprio(1);
      #pragma unroll
      for(int mi = 0; mi < 2; mi++)
        #pragma unroll
        for(int nr = 0; nr < 4; nr++)
          #pragma unroll
          for(int ks = 0; ks < 2; ks++)
            acc[q * 2 + mi][nr] = __builtin_amdgcn_mfma_f32_16x16x32_bf16(
                afr[mi][ks], bfr[nr][ks], acc[q * 2 + mi][nr], 0, 0, 0);
      __builtin_amdgcn_s_setprio(0);
      __builtin_amdgcn_sched_barrier(0);
      if(q == 3){
        if(t < 30)       asm volatile("s_waitcnt vmcnt(4)" ::: "memory");
        else if(t == 30) asm volatile("s_waitcnt vmcnt(0)" ::: "memory");
      }
      __builtin_amdgcn_s_barrier();
    }
  }

  // epilogue: fused tanh + bf16 store
  const int r0 = m0 + wm * 128 + (lane >> 4) * 4;
  const int c0 = n0 + wn * 64 + frow;
  #pragma unroll
  for(int mr = 0; mr < 8; mr++)
    #pragma unroll
    for(int nr = 0; nr < 4; nr++)
      #pragma unroll
      for(int r = 0; r < 4; r++)
        Ct[(size_t)(r0 + mr * 16 + r) * DD + c0 + nr * 16] = f2bf(fast_tanh(acc[mr][nr][r]));
}

// ---------- gemmB: scores_c = W_p2 . relu(tanh_buf @ W_p1a^T + bias2) + b_p2 ----------
__global__ __launch_bounds__(256) void gemmB_kernel(
    const unsigned short* __restrict__ A, const unsigned short* __restrict__ B,
    const int* __restrict__ mcount, const float* __restrict__ bias2,
    const float* __restrict__ w2, const float* __restrict__ bp2,
    float* __restrict__ scores)
{
  __shared__ unsigned short At[64 * 64];     // 8 KB
  __shared__ unsigned short Bt[256 * 64];    // 32 KB
  __shared__ float sred[4][64];
  const int tid = threadIdx.x, lane = tid & 63, w = tid >> 6;
  const int m0 = blockIdx.x * 64;
  if(m0 >= mcount[1]) return;
  const int srow = lane >> 3;
  const int scol = ((lane & 7) ^ srow) * 16;
  const int xorv = (lane & 7) << 4;
  f32x4 acc[4][4] = {};
  for(int kt = 0; kt < DD; kt += 64){
    __syncthreads();
    #pragma unroll
    for(int i = 0; i < 2; i++){
      int r8 = (w * 2 + i) * 8;
      gl_lds16((const char*)(A + (size_t)(m0 + r8 + srow) * DD + kt) + scol,
               (char*)At + r8 * 128);
    }
    #pragma unroll
    for(int i = 0; i < 8; i++){
      int r8 = (w * 8 + i) * 8;
      gl_lds16((const char*)(B + (size_t)(r8 + srow) * DD + kt) + scol,
               (char*)Bt + r8 * 128);
    }
    __syncthreads();
    #pragma unroll
    for(int ks = 0; ks < 2; ks++){
      const int cb = (ks * 4 + (lane >> 4)) * 16;
      bf16x8 af[4], bv[4];
      #pragma unroll
      for(int i = 0; i < 4; i++){
        af[i] = *(const bf16x8*)((const char*)At + (i * 16 + (lane & 15)) * 128 + (cb ^ xorv));
        bv[i] = *(const bf16x8*)((const char*)Bt + (w * 64 + i * 16 + (lane & 15)) * 128 + (cb ^ xorv));
      }
      #pragma unroll
      for(int i = 0; i < 4; i++)
        #pragma unroll
        for(int j = 0; j < 4; j++)
          acc[i][j] = __builtin_amdgcn_mfma_f32_16x16x32_bf16(af[i], bv[j], acc[i][j], 0, 0, 0);
    }
  }
  float w2v[4], b2v[4];
  #pragma unroll
  for(int in = 0; in < 4; in++){
    int n = w * 64 + in * 16 + (lane & 15);
    w2v[in] = (n < HH) ? w2[n] : 0.f;
    b2v[in] = bias2[n];
  }
  #pragma unroll
  for(int im = 0; im < 4; im++){
    #pragma unroll
    for(int r = 0; r < 4; r++){
      float s = 0.f;
      #pragma unroll
      for(int in = 0; in < 4; in++){
        float h = acc[im][in][r] + b2v[in];
        s += (h > 0.f ? h : 0.f) * w2v[in];
      }
      s += __shfl_xor(s, 1); s += __shfl_xor(s, 2);
      s += __shfl_xor(s, 4); s += __shfl_xor(s, 8);
      if((lane & 15) == 0) sred[w][im * 16 + (lane >> 4) * 4 + r] = s;
    }
  }
  __syncthreads();
  if(tid < 64)
    scores[m0 + tid] = sred[0][tid] + sred[1][tid] + sred[2][tid] + sred[3][tid] + bp2[0];
}

// ---------- scatter compacted scores back to full index space ----------
__global__ void scatter_kernel(const float* __restrict__ sc, const int* __restrict__ idx,
                               const int* __restrict__ mcount, float* __restrict__ sf)
{
  int j = blockIdx.x * 256 + threadIdx.x;
  if(j < mcount[0]) sf[idx[j]] = sc[j];
}

// ---------- masked softmax ----------
__global__ __launch_bounds__(1024) void softmax_kernel(
    const float* __restrict__ scores, const int* __restrict__ mask, float* __restrict__ attn)
{
  __shared__ float red[16];
  const int tid = threadIdx.x;
  float m = -3.0e38f;
  for(int i = tid; i < SS; i += 1024) if(mask[i] == 0) m = fmaxf(m, scores[i]);
  #pragma unroll
  for(int o = 32; o; o >>= 1) m = fmaxf(m, __shfl_xor(m, o));
  if((tid & 63) == 0) red[tid >> 6] = m;
  __syncthreads();
  float M = -3.0e38f;
  #pragma unroll
  for(int i = 0; i < 16; i++) M = fmaxf(M, red[i]);
  __syncthreads();
  float s = 0.f;
  for(int i = tid; i < SS; i += 1024) if(mask[i] == 0) s += __expf(scores[i] - M);
  #pragma unroll
  for(int o = 32; o; o >>= 1) s += __shfl_xor(s, o);
  if((tid & 63) == 0) red[tid >> 6] = s;
  __syncthreads();
  float T = 0.f;
  #pragma unroll
  for(int i = 0; i < 16; i++) T += red[i];
  const float inv = 1.0f / T;
  for(int i = tid; i < SS; i += 1024)
    attn[i] = (mask[i] == 0) ? __expf(scores[i] - M) * inv : 0.f;
}

// ---------- ctx = attn @ enc (512 blocks, skip attn==0 rows) ----------
__global__ __launch_bounds__(256) void ctxp_kernel(
    const float* __restrict__ attn, const float* __restrict__ enc, float* __restrict__ part)
{
  const int b = blockIdx.x, t = threadIdx.x;
  float a0=0,a1=0,a2=0,a3=0,a4=0,a5=0,a6=0,a7=0;
  const float* base = enc + (size_t)b * 32 * DD + t * 8;
  const float* ap = attn + b * 32;
  for(int s = 0; s < 32; s++){
    float av = ap[s];
    if(av != 0.f){
      const float4* p = (const float4*)(base + (size_t)s * DD);
      float4 x = p[0], y = p[1];
      a0 += av * x.x; a1 += av * x.y; a2 += av * x.z; a3 += av * x.w;
      a4 += av * y.x; a5 += av * y.y; a6 += av * y.z; a7 += av * y.w;
    }
  }
  float* o = part + (size_t)b * DD + t * 8;
  o[0]=a0; o[1]=a1; o[2]=a2; o[3]=a3; o[4]=a4; o[5]=a5; o[6]=a6; o[7]=a7;
}

__global__ void ctxr_kernel(const float* __restrict__ part, float* __restrict__ out){
  const int d = blockIdx.x * 256 + threadIdx.x;
  float s = 0.f;
  for(int b = 0; b < 512; b++) s += part[(size_t)b * DD + d];
  out[d] = s;
}

// ---------- launch ----------
extern "C" void kernel_launch(void* const* d_in, const int* in_sizes, int n_in,
                              void* d_out, int out_size, void* d_ws, size_t ws_size,
                              hipStream_t stream)
{
  const float* s_prev = (const float*)d_in[0];
  const float* enc    = (const float*)d_in[1];
  const float* cmr    = (const float*)d_in[2];
  const int*   mask   = (const int*)d_in[3];
  const float* W_info = (const float*)d_in[4];
  const float* W_ctx  = (const float*)d_in[5];
  const float* W_q    = (const float*)d_in[6];
  const float* b_q    = (const float*)d_in[7];
  const float* W_p1   = (const float*)d_in[8];
  const float* b_p1   = (const float*)d_in[9];
  const float* W_p2   = (const float*)d_in[10];
  const float* b_p2   = (const float*)d_in[11];
  float* out = (float*)d_out;

  char* ws = (char*)d_ws;
  unsigned short* encb    = (unsigned short*)(ws);                   // 67108864 B
  unsigned short* tanhbuf = (unsigned short*)(ws + 67108864);        // 67108864 B
  unsigned short* wctxb   = (unsigned short*)(ws + 134217728);       //  8388608 B
  unsigned short* wp1ab   = (unsigned short*)(ws + 142606336);       //  1048576 B
  int*   idx     = (int*)(ws + 143654912);                           //    65536 B
  float* scoresc = (float*)(ws + 143720448);                         //    65536 B
  float* scoresf = (float*)(ws + 143785984);                         //    65536 B
  float* twq     = (float*)(ws + 143851520);                         //     8192 B
  float* tdh     = (float*)(ws + 143859712);                         //     8192 B
  float* bias2   = (float*)(ws + 143867904);                         //     1024 B
  int*   mcount  = (int*)(ws + 143868928);                           //      256 B
  float* part    = (float*)(ws);   // aliases encb (dead after gemmA)

  scan_kernel<<<1, 1024, 0, stream>>>(mask, idx, mcount);
  conv_enc_kernel<<<16384, 256, 0, stream>>>(enc, idx, mcount, encb);
  conv_wctx_kernel<<<512, 256, 0, stream>>>(W_ctx, wctxb);
  conv_wp1a_kernel<<<256, 256, 0, stream>>>(W_p1, wp1ab);
  vec_kernel<<<1024, 256, 0, stream>>>(s_prev, cmr, W_q, b_q, W_info, twq, tdh);
  bias2_kernel<<<64, 256, 0, stream>>>(W_p1, b_p1, twq, tdh, bias2);
  gemmA_kernel<<<512, 512, 0, stream>>>(encb, wctxb, mcount, tanhbuf);
  gemmB_kernel<<<256, 256, 0, stream>>>(tanhbuf, wp1ab, mcount, bias2, W_p2, b_p2, scoresc);
  scatter_kernel<<<64, 256, 0, stream>>>(scoresc, idx, mcount, scoresf);
  softmax_kernel<<<1, 1024, 0, stream>>>(scoresf, mask, out);
  ctxp_kernel<<<512, 256, 0, stream>>>(out, enc, part);
  ctxr_kernel<<<8, 256, 0, stream>>>(part, out + SS);
}